// Round 2
// baseline (3174.905 us; speedup 1.0000x reference)
//
#include <hip/hip_runtime.h>

#define N_USER 100000
#define N_NODE 150000
#define N_EDGE 2400000
#define DIM 64
#define BPAIR 4096
#define NEG_SLOPE 0.01f

// ---------------- CSR build ----------------

__global__ void count_kernel(const int* __restrict__ rows, int* __restrict__ cnt) {
    int i = blockIdx.x * blockDim.x + threadIdx.x;
    if (i < N_EDGE) atomicAdd(&cnt[rows[i]], 1);
}

// 256-element block-wise inclusive scan; incl = row_ptr + 1
__global__ void scan1_kernel(const int* __restrict__ cnt, int* __restrict__ incl,
                             int* __restrict__ bsums) {
    __shared__ int s[256];
    int t = threadIdx.x;
    int i = blockIdx.x * 256 + t;
    s[t] = (i < N_NODE) ? cnt[i] : 0;
    __syncthreads();
    for (int off = 1; off < 256; off <<= 1) {
        int add = (t >= off) ? s[t - off] : 0;
        __syncthreads();
        s[t] += add;
        __syncthreads();
    }
    if (i < N_NODE) incl[i] = s[t];
    if (t == 255) bsums[blockIdx.x] = s[255];
}

__global__ void scan2_kernel(int* __restrict__ bsums, int nblk) {
    __shared__ int s[1024];
    int t = threadIdx.x;
    s[t] = (t < nblk) ? bsums[t] : 0;
    __syncthreads();
    for (int off = 1; off < 1024; off <<= 1) {
        int add = (t >= off) ? s[t - off] : 0;
        __syncthreads();
        s[t] += add;
        __syncthreads();
    }
    if (t < nblk) bsums[t] = s[t];
}

__global__ void scan3_kernel(int* __restrict__ row_ptr, const int* __restrict__ bsums) {
    int i = blockIdx.x * 256 + threadIdx.x;
    if (i == 0) row_ptr[0] = 0;
    if (i < N_NODE && blockIdx.x > 0) row_ptr[1 + i] += bsums[blockIdx.x - 1];
}

__global__ void scatter_kernel(const int* __restrict__ rows, const int* __restrict__ cols,
                               const float* __restrict__ vals, const int* __restrict__ row_ptr,
                               int* __restrict__ cursor, int2* __restrict__ edges) {
    int i = blockIdx.x * blockDim.x + threadIdx.x;
    if (i < N_EDGE) {
        int r = rows[i];
        int p = row_ptr[r] + atomicAdd(&cursor[r], 1);
        edges[p] = make_int2(cols[i], __float_as_int(vals[i]));
    }
}

// ---------------- fused SpMM + dense layer ----------------
// One wave per row: lane d owns feature dim d. Edge loop: unroll-8, all 8
// int2 edge loads issued together, then 8 independent 256B gathers in
// flight. Dense transform: W tiles in LDS ([64][64], reads are lane-
// consecutive -> free 2-way conflict), h broadcast via v_readlane from
// registers (no LDS round-trip), 4 accumulator chains.
__global__ __launch_bounds__(512, 8) void layer_kernel(
    const int* __restrict__ row_ptr, const int2* __restrict__ edges,
    const float* __restrict__ fin, float* __restrict__ fout,
    const float* __restrict__ W1l, const float* __restrict__ b1l,
    const float* __restrict__ W2l, const float* __restrict__ b2l) {
    __shared__ float w1t[64][64];   // w1t[k][d] = W1l[d*64+k]
    __shared__ float w2t[64][64];
    int t = threadIdx.x;
    for (int idx = t; idx < 4096; idx += 512) {
        int d = idx >> 6, k = idx & 63;
        w1t[k][d] = W1l[idx];
        w2t[k][d] = W2l[idx];
    }
    __syncthreads();
    int lane = t & 63;
    int gwave = (blockIdx.x * 512 + t) >> 6;
    int nwave = (gridDim.x * 512) >> 6;
    float bsum = b1l[lane] + b2l[lane];
    for (int r = gwave; r < N_NODE; r += nwave) {
        int e0 = row_ptr[r], e1 = row_ptr[r + 1];
        float f = fin[((size_t)r << 6) | lane];   // independent: issue early
        float a0 = 0.f, a1 = 0.f;
        int j = e0;
        for (; j + 7 < e1; j += 8) {
            int2 e[8];
#pragma unroll
            for (int u = 0; u < 8; ++u) e[u] = edges[j + u];
            float g[8];
#pragma unroll
            for (int u = 0; u < 8; ++u) g[u] = fin[((size_t)e[u].x << 6) | lane];
#pragma unroll
            for (int u = 0; u < 8; ++u) {
                float v = __int_as_float(e[u].y);
                if (u & 1) a1 += v * g[u]; else a0 += v * g[u];
            }
        }
        for (; j < e1; ++j) {
            int2 e = edges[j];
            a0 += __int_as_float(e.y) * fin[((size_t)e.x << 6) | lane];
        }
        float acc = a0 + a1;
        float h1 = acc + f;
        float h2 = acc * f;
        float o0 = bsum, o1 = 0.f, o2 = 0.f, o3 = 0.f;
#pragma unroll
        for (int k = 0; k < 64; k += 2) {
            float h1a = __int_as_float(__builtin_amdgcn_readlane(__float_as_int(h1), k));
            float h2a = __int_as_float(__builtin_amdgcn_readlane(__float_as_int(h2), k));
            float h1b = __int_as_float(__builtin_amdgcn_readlane(__float_as_int(h1), k + 1));
            float h2b = __int_as_float(__builtin_amdgcn_readlane(__float_as_int(h2), k + 1));
            o0 += h1a * w1t[k][lane];
            o1 += h2a * w2t[k][lane];
            o2 += h1b * w1t[k + 1][lane];
            o3 += h2b * w2t[k + 1][lane];
        }
        float o = (o0 + o1) + (o2 + o3);
        o = (o > 0.f) ? o : NEG_SLOPE * o;
        fout[((size_t)r << 6) | lane] = o;
    }
}

// gather the 8192 selected rows (4096 users, 4096 items) of this layer's output
__global__ void gather_kernel(float* __restrict__ dst, const float* __restrict__ src,
                              const int* __restrict__ users, const int* __restrict__ items) {
    int t = threadIdx.x;
    int p = blockIdx.x * 4 + (t >> 6);
    int lane = t & 63;
    if (p < 2 * BPAIR) {
        int node = (p < BPAIR) ? users[p] : (N_USER + items[p - BPAIR]);
        dst[((size_t)p << 6) | lane] = src[((size_t)node << 6) | lane];
    }
}

// one wave per pair: lane d computes user_emb[d], item_emb[d] with float4
// reads of lane's own Wt row (64 KB matrix, L1/L2-hot); 64-lane reduce.
__global__ __launch_bounds__(256) void score_kernel(
    const float* __restrict__ features, const float* __restrict__ sel,
    const int* __restrict__ users, const int* __restrict__ items,
    const float* __restrict__ Wt, const float* __restrict__ bt,
    float* __restrict__ out) {
    __shared__ float hu[4][256];
    __shared__ float hv[4][256];
    int t = threadIdx.x;
    int wave = t >> 6, lane = t & 63;
    int gwave = (blockIdx.x * 256 + t) >> 6;
    int nwave = (gridDim.x * 256) >> 6;
    float btv = bt[lane];
    const float4* wrow = (const float4*)(Wt + (size_t)lane * 256);
    for (int p = gwave; p < BPAIR; p += nwave) {
        int u = users[p];
        int v = N_USER + items[p];
        hu[wave][lane] = features[((size_t)u << 6) | lane];
        hv[wave][lane] = features[((size_t)v << 6) | lane];
#pragma unroll
        for (int l = 0; l < 3; ++l) {
            hu[wave][64 + l * 64 + lane] = sel[(((size_t)l * 2 * BPAIR + p) << 6) | lane];
            hv[wave][64 + l * 64 + lane] = sel[(((size_t)l * 2 * BPAIR + BPAIR + p) << 6) | lane];
        }
        // wave-local LDS RAW: compiler inserts lgkmcnt wait; no barrier needed
        const float4* hu4 = (const float4*)&hu[wave][0];
        const float4* hv4 = (const float4*)&hv[wave][0];
        float pu0 = btv, pu1 = 0.f, pv0 = btv, pv1 = 0.f;
#pragma unroll 8
        for (int kk = 0; kk < 64; ++kk) {
            float4 w = wrow[kk];
            float4 a = hu4[kk];
            float4 b = hv4[kk];
            pu0 += w.x * a.x + w.z * a.z;
            pu1 += w.y * a.y + w.w * a.w;
            pv0 += w.x * b.x + w.z * b.z;
            pv1 += w.y * b.y + w.w * b.w;
        }
        float s = (pu0 + pu1) * (pv0 + pv1);
        for (int m = 32; m >= 1; m >>= 1) s += __shfl_xor(s, m, 64);
        if (lane == 0) out[p] = s;
    }
}

extern "C" void kernel_launch(void* const* d_in, const int* in_sizes, int n_in,
                              void* d_out, int out_size, void* d_ws, size_t ws_size,
                              hipStream_t stream) {
    const float* features = (const float*)d_in[0];
    const int*   rows     = (const int*)d_in[1];
    const int*   cols     = (const int*)d_in[2];
    const float* vals     = (const float*)d_in[3];
    const int*   users    = (const int*)d_in[4];
    const int*   items    = (const int*)d_in[5];
    const float* W1       = (const float*)d_in[6];
    const float* b1       = (const float*)d_in[7];
    const float* W2       = (const float*)d_in[8];
    const float* b2       = (const float*)d_in[9];
    const float* Wt       = (const float*)d_in[10];
    const float* bt       = (const float*)d_in[11];
    float* out = (float*)d_out;

    char* ws = (char*)d_ws;
    size_t off = 0;
    auto alloc = [&](size_t bytes) -> void* {
        void* p = ws + off;
        off += (bytes + 255) & ~(size_t)255;
        return p;
    };
    int*   row_ptr = (int*)alloc((N_NODE + 1) * sizeof(int));
    int*   cnt     = (int*)alloc(N_NODE * sizeof(int));
    int*   cursor  = (int*)alloc(N_NODE * sizeof(int));
    int*   bsums   = (int*)alloc(4096);
    int2*  edges   = (int2*)alloc((size_t)N_EDGE * sizeof(int2));
    float* f0      = (float*)alloc((size_t)N_NODE * DIM * sizeof(float));
    float* f1      = (float*)alloc((size_t)N_NODE * DIM * sizeof(float));
    float* sel     = (float*)alloc((size_t)3 * 2 * BPAIR * DIM * sizeof(float));

    // cnt and cursor are contiguous padded regions; zero both
    hipMemsetAsync(cnt, 0, 2 * (((size_t)N_NODE * sizeof(int) + 255) & ~(size_t)255), stream);

    int eblocks = (N_EDGE + 255) / 256;
    int nblk = (N_NODE + 255) / 256;  // 586 <= 1024
    count_kernel<<<eblocks, 256, 0, stream>>>(rows, cnt);
    scan1_kernel<<<nblk, 256, 0, stream>>>(cnt, row_ptr + 1, bsums);
    scan2_kernel<<<1, 1024, 0, stream>>>(bsums, nblk);
    scan3_kernel<<<nblk, 256, 0, stream>>>(row_ptr, bsums);
    scatter_kernel<<<eblocks, 256, 0, stream>>>(rows, cols, vals, row_ptr, cursor, edges);

    const float* fin = features;
    float* fbuf[2] = {f0, f1};
    for (int l = 0; l < 3; ++l) {
        float* fout = fbuf[l & 1];
        layer_kernel<<<2048, 512, 0, stream>>>(row_ptr, edges, fin, fout,
                                               W1 + (size_t)l * DIM * DIM, b1 + (size_t)l * DIM,
                                               W2 + (size_t)l * DIM * DIM, b2 + (size_t)l * DIM);
        gather_kernel<<<(2 * BPAIR) / 4, 256, 0, stream>>>(sel + (size_t)l * 2 * BPAIR * DIM,
                                                           fout, users, items);
        fin = fout;
    }
    score_kernel<<<256, 256, 0, stream>>>(features, sel, users, items, Wt, bt, out);
}

// Round 5
// 1830.931 us; speedup vs baseline: 1.7340x; 1.7340x over previous
//
#include <hip/hip_runtime.h>

#define N_USER 100000
#define N_NODE 150000
#define N_EDGE 2400000
#define DIM 64
#define BPAIR 4096
#define NEG_SLOPE 0.01f

// ---------------- CSR build ----------------

__global__ void count_kernel(const int* __restrict__ rows, int* __restrict__ cnt) {
    int i = blockIdx.x * blockDim.x + threadIdx.x;
    if (i < N_EDGE) atomicAdd(&cnt[rows[i]], 1);
}

// 256-element block-wise inclusive scan; incl = row_ptr + 1
__global__ void scan1_kernel(const int* __restrict__ cnt, int* __restrict__ incl,
                             int* __restrict__ bsums) {
    __shared__ int s[256];
    int t = threadIdx.x;
    int i = blockIdx.x * 256 + t;
    s[t] = (i < N_NODE) ? cnt[i] : 0;
    __syncthreads();
    for (int off = 1; off < 256; off <<= 1) {
        int add = (t >= off) ? s[t - off] : 0;
        __syncthreads();
        s[t] += add;
        __syncthreads();
    }
    if (i < N_NODE) incl[i] = s[t];
    if (t == 255) bsums[blockIdx.x] = s[255];
}

__global__ void scan2_kernel(int* __restrict__ bsums, int nblk) {
    __shared__ int s[1024];
    int t = threadIdx.x;
    s[t] = (t < nblk) ? bsums[t] : 0;
    __syncthreads();
    for (int off = 1; off < 1024; off <<= 1) {
        int add = (t >= off) ? s[t - off] : 0;
        __syncthreads();
        s[t] += add;
        __syncthreads();
    }
    if (t < nblk) bsums[t] = s[t];
}

__global__ void scan3_kernel(int* __restrict__ row_ptr, const int* __restrict__ bsums) {
    int i = blockIdx.x * 256 + threadIdx.x;
    if (i == 0) row_ptr[0] = 0;
    if (i < N_NODE && blockIdx.x > 0) row_ptr[1 + i] += bsums[blockIdx.x - 1];
}

__global__ void scatter_kernel(const int* __restrict__ rows, const int* __restrict__ cols,
                               const float* __restrict__ vals, const int* __restrict__ row_ptr,
                               int* __restrict__ cursor, int2* __restrict__ edges) {
    int i = blockIdx.x * blockDim.x + threadIdx.x;
    if (i < N_EDGE) {
        int r = rows[i];
        int p = row_ptr[r] + atomicAdd(&cursor[r], 1);
        edges[p] = make_int2(cols[i], __float_as_int(vals[i]));
    }
}

// ---------------- fused SpMM + dense layer ----------------
// One wave per row: lane d owns feature dim d. Edge loop: predicated
// unroll-8 (no serial tail) -> 8 independent 256B gathers in flight.
// Dense transform: W tiles in LDS, k-major [64][65] pad (conflict-free
// reads AND staging writes, ds_read2-fusable); h broadcast via v_readlane
// from registers; 4 accumulator chains.
// __launch_bounds__(256,4): 128-VGPR cap, ~100 live -> no spill (the
// (512,8)->32-VGPR spill disaster of round 2 cost 4x).
__global__ __launch_bounds__(256, 4) void layer_kernel(
    const int* __restrict__ row_ptr, const int2* __restrict__ edges,
    const float* __restrict__ fin, float* __restrict__ fout,
    const float* __restrict__ W1l, const float* __restrict__ b1l,
    const float* __restrict__ W2l, const float* __restrict__ b2l) {
    __shared__ float w1t[64][65];   // w1t[k][d] = W1l[d*64+k]
    __shared__ float w2t[64][65];
    int t = threadIdx.x;
    for (int idx = t; idx < 4096; idx += 256) {
        int d = idx >> 6, k = idx & 63;
        w1t[k][d] = W1l[idx];
        w2t[k][d] = W2l[idx];
    }
    __syncthreads();
    int lane = t & 63;
    int gwave = (blockIdx.x * 256 + t) >> 6;
    int nwave = (gridDim.x * 256) >> 6;
    float bsum = b1l[lane] + b2l[lane];
    for (int r = gwave; r < N_NODE; r += nwave) {
        int e0 = row_ptr[r], e1 = row_ptr[r + 1];
        float f = fin[((size_t)r << 6) | lane];   // independent: issue early
        float a0 = 0.f, a1 = 0.f;
        for (int j = e0; j < e1; j += 8) {
            int2 e[8];
#pragma unroll
            for (int u = 0; u < 8; ++u) {
                int jj = (j + u < e1) ? (j + u) : e0;   // clamp: always valid
                e[u] = edges[jj];
            }
            float g[8];
#pragma unroll
            for (int u = 0; u < 8; ++u) g[u] = fin[((size_t)e[u].x << 6) | lane];
#pragma unroll
            for (int u = 0; u < 8; ++u) {
                float v = (j + u < e1) ? __int_as_float(e[u].y) : 0.f;
                if (u & 1) a1 += v * g[u]; else a0 += v * g[u];
            }
        }
        float acc = a0 + a1;
        float h1 = acc + f;
        float h2 = acc * f;
        float o0 = bsum, o1 = 0.f, o2 = 0.f, o3 = 0.f;
#pragma unroll
        for (int k = 0; k < 64; k += 2) {
            float w1a = w1t[k][lane],     w2a = w2t[k][lane];
            float w1b = w1t[k + 1][lane], w2b = w2t[k + 1][lane];
            float h1a = __int_as_float(__builtin_amdgcn_readlane(__float_as_int(h1), k));
            float h2a = __int_as_float(__builtin_amdgcn_readlane(__float_as_int(h2), k));
            float h1b = __int_as_float(__builtin_amdgcn_readlane(__float_as_int(h1), k + 1));
            float h2b = __int_as_float(__builtin_amdgcn_readlane(__float_as_int(h2), k + 1));
            o0 += h1a * w1a;
            o1 += h2a * w2a;
            o2 += h1b * w1b;
            o3 += h2b * w2b;
        }
        float o = (o0 + o1) + (o2 + o3);
        o = (o > 0.f) ? o : NEG_SLOPE * o;
        fout[((size_t)r << 6) | lane] = o;
    }
}

// gather the 8192 selected rows (4096 users, 4096 items) of this layer's output
__global__ void gather_kernel(float* __restrict__ dst, const float* __restrict__ src,
                              const int* __restrict__ users, const int* __restrict__ items) {
    int t = threadIdx.x;
    int p = blockIdx.x * 4 + (t >> 6);
    int lane = t & 63;
    if (p < 2 * BPAIR) {
        int node = (p < BPAIR) ? users[p] : (N_USER + items[p - BPAIR]);
        dst[((size_t)p << 6) | lane] = src[((size_t)node << 6) | lane];
    }
}

// one wave per pair: lane d computes user_emb[d], item_emb[d] with float4
// reads of lane's own Wt row (64 KB matrix, L1/L2-hot); 64-lane reduce.
__global__ __launch_bounds__(256) void score_kernel(
    const float* __restrict__ features, const float* __restrict__ sel,
    const int* __restrict__ users, const int* __restrict__ items,
    const float* __restrict__ Wt, const float* __restrict__ bt,
    float* __restrict__ out) {
    __shared__ float hu[4][256];
    __shared__ float hv[4][256];
    int t = threadIdx.x;
    int wave = t >> 6, lane = t & 63;
    int gwave = (blockIdx.x * 256 + t) >> 6;
    int nwave = (gridDim.x * 256) >> 6;
    float btv = bt[lane];
    const float4* wrow = (const float4*)(Wt + (size_t)lane * 256);
    for (int p = gwave; p < BPAIR; p += nwave) {
        int u = users[p];
        int v = N_USER + items[p];
        hu[wave][lane] = features[((size_t)u << 6) | lane];
        hv[wave][lane] = features[((size_t)v << 6) | lane];
#pragma unroll
        for (int l = 0; l < 3; ++l) {
            hu[wave][64 + l * 64 + lane] = sel[(((size_t)l * 2 * BPAIR + p) << 6) | lane];
            hv[wave][64 + l * 64 + lane] = sel[(((size_t)l * 2 * BPAIR + BPAIR + p) << 6) | lane];
        }
        // wave-local LDS RAW: compiler inserts lgkmcnt wait; no barrier needed
        const float4* hu4 = (const float4*)&hu[wave][0];
        const float4* hv4 = (const float4*)&hv[wave][0];
        float pu0 = btv, pu1 = 0.f, pv0 = btv, pv1 = 0.f;
#pragma unroll 8
        for (int kk = 0; kk < 64; ++kk) {
            float4 w = wrow[kk];
            float4 a = hu4[kk];
            float4 b = hv4[kk];
            pu0 += w.x * a.x + w.z * a.z;
            pu1 += w.y * a.y + w.w * a.w;
            pv0 += w.x * b.x + w.z * b.z;
            pv1 += w.y * b.y + w.w * b.w;
        }
        float s = (pu0 + pu1) * (pv0 + pv1);
        for (int m = 32; m >= 1; m >>= 1) s += __shfl_xor(s, m, 64);
        if (lane == 0) out[p] = s;
    }
}

extern "C" void kernel_launch(void* const* d_in, const int* in_sizes, int n_in,
                              void* d_out, int out_size, void* d_ws, size_t ws_size,
                              hipStream_t stream) {
    const float* features = (const float*)d_in[0];
    const int*   rows     = (const int*)d_in[1];
    const int*   cols     = (const int*)d_in[2];
    const float* vals     = (const float*)d_in[3];
    const int*   users    = (const int*)d_in[4];
    const int*   items    = (const int*)d_in[5];
    const float* W1       = (const float*)d_in[6];
    const float* b1       = (const float*)d_in[7];
    const float* W2       = (const float*)d_in[8];
    const float* b2       = (const float*)d_in[9];
    const float* Wt       = (const float*)d_in[10];
    const float* bt       = (const float*)d_in[11];
    float* out = (float*)d_out;

    char* ws = (char*)d_ws;
    size_t off = 0;
    auto alloc = [&](size_t bytes) -> void* {
        void* p = ws + off;
        off += (bytes + 255) & ~(size_t)255;
        return p;
    };
    int*   row_ptr = (int*)alloc((N_NODE + 1) * sizeof(int));
    int*   cnt     = (int*)alloc(N_NODE * sizeof(int));
    int*   cursor  = (int*)alloc(N_NODE * sizeof(int));
    int*   bsums   = (int*)alloc(4096);
    int2*  edges   = (int2*)alloc((size_t)N_EDGE * sizeof(int2));
    float* f0      = (float*)alloc((size_t)N_NODE * DIM * sizeof(float));
    float* f1      = (float*)alloc((size_t)N_NODE * DIM * sizeof(float));
    float* sel     = (float*)alloc((size_t)3 * 2 * BPAIR * DIM * sizeof(float));

    // cnt and cursor are contiguous padded regions; zero both
    hipMemsetAsync(cnt, 0, 2 * (((size_t)N_NODE * sizeof(int) + 255) & ~(size_t)255), stream);

    int eblocks = (N_EDGE + 255) / 256;
    int nblk = (N_NODE + 255) / 256;  // 586 <= 1024
    count_kernel<<<eblocks, 256, 0, stream>>>(rows, cnt);
    scan1_kernel<<<nblk, 256, 0, stream>>>(cnt, row_ptr + 1, bsums);
    scan2_kernel<<<1, 1024, 0, stream>>>(bsums, nblk);
    scan3_kernel<<<nblk, 256, 0, stream>>>(row_ptr, bsums);
    scatter_kernel<<<eblocks, 256, 0, stream>>>(rows, cols, vals, row_ptr, cursor, edges);

    const float* fin = features;
    float* fbuf[2] = {f0, f1};
    for (int l = 0; l < 3; ++l) {
        float* fout = fbuf[l & 1];
        layer_kernel<<<2048, 256, 0, stream>>>(row_ptr, edges, fin, fout,
                                               W1 + (size_t)l * DIM * DIM, b1 + (size_t)l * DIM,
                                               W2 + (size_t)l * DIM * DIM, b2 + (size_t)l * DIM);
        gather_kernel<<<(2 * BPAIR) / 4, 256, 0, stream>>>(sel + (size_t)l * 2 * BPAIR * DIM,
                                                           fout, users, items);
        fin = fout;
    }
    score_kernel<<<256, 256, 0, stream>>>(features, sel, users, items, Wt, bt, out);
}

// Round 6
// 1030.047 us; speedup vs baseline: 3.0823x; 1.7775x over previous
//
#include <hip/hip_runtime.h>

#define N_USER 100000
#define N_NODE 150000
#define N_EDGE 2400000
#define DIM 64
#define BPAIR 4096
#define NEG_SLOPE 0.01f
#define RPG 4                              // rows per wave-group (150000 % 4 == 0)
#define NGROUP (N_NODE / RPG)              // 37500
#define EPAD_CAP (N_EDGE + 8 * N_NODE)     // padded CSR capacity

// ---------------- CSR build (padded to 8-edge multiples per row) ----------------
// rank[i] = arrival order within row (from count pass) -> scatter needs no atomics.

__global__ void count_rank_kernel(const int* __restrict__ rows, int* __restrict__ cnt,
                                  int* __restrict__ rank) {
    int i = blockIdx.x * blockDim.x + threadIdx.x;
    if (i < N_EDGE) rank[i] = atomicAdd(&cnt[rows[i]], 1);
}

// scan of PADDED counts ((cnt+7)&~7); incl = row_ptr + 1
__global__ void scan1_kernel(const int* __restrict__ cnt, int* __restrict__ incl,
                             int* __restrict__ bsums) {
    __shared__ int s[256];
    int t = threadIdx.x;
    int i = blockIdx.x * 256 + t;
    s[t] = (i < N_NODE) ? ((cnt[i] + 7) & ~7) : 0;
    __syncthreads();
    for (int off = 1; off < 256; off <<= 1) {
        int add = (t >= off) ? s[t - off] : 0;
        __syncthreads();
        s[t] += add;
        __syncthreads();
    }
    if (i < N_NODE) incl[i] = s[t];
    if (t == 255) bsums[blockIdx.x] = s[255];
}

__global__ void scan2_kernel(int* __restrict__ bsums, int nblk) {
    __shared__ int s[1024];
    int t = threadIdx.x;
    s[t] = (t < nblk) ? bsums[t] : 0;
    __syncthreads();
    for (int off = 1; off < 1024; off <<= 1) {
        int add = (t >= off) ? s[t - off] : 0;
        __syncthreads();
        s[t] += add;
        __syncthreads();
    }
    if (t < nblk) bsums[t] = s[t];
}

__global__ void scan3_kernel(int* __restrict__ row_ptr, const int* __restrict__ bsums) {
    int i = blockIdx.x * 256 + threadIdx.x;
    if (i == 0) row_ptr[0] = 0;
    if (i < N_NODE && blockIdx.x > 0) row_ptr[1 + i] += bsums[blockIdx.x - 1];
}

// edges buffer pre-zeroed -> pad slots are (col=0, val=0), harmless in SpMM
__global__ void scatter_kernel(const int* __restrict__ rows, const int* __restrict__ cols,
                               const float* __restrict__ vals, const int* __restrict__ rank,
                               const int* __restrict__ row_ptr, int2* __restrict__ edges) {
    int i = blockIdx.x * blockDim.x + threadIdx.x;
    if (i < N_EDGE) {
        int p = row_ptr[rows[i]] + rank[i];
        edges[p] = make_int2(cols[i], __float_as_int(vals[i]));
    }
}

// ---------------- fused SpMM + dense layer ----------------
// One wave per 4-row group, lane d owns feature dim d.
// Edge phase: rows padded to 8-edge multiples -> no predication, no tail;
//   int4 loads (2 edges each), 8 independent 256B gathers in flight.
// Dense phase: W1/W2 read from GLOBAL as float4 (row-major [d][k] is exactly
//   the per-lane layout; 32KB, L1-resident) -> no LDS staging, no barrier.
//   h broadcast via same-address float4 LDS reads; W loads amortized over
//   4 rows; 2 FMA chains per row.
// NOTE: plain __launch_bounds__(256). A min-waves 2nd arg makes this
// toolchain cap VGPR at 256/arg2 (rounds 2 & 5: 8->32, 4->64) and spill.
__global__ __launch_bounds__(256) void layer_kernel(
    const int* __restrict__ row_ptr, const int2* __restrict__ edges,
    const float* __restrict__ fin, float* __restrict__ fout,
    const float* __restrict__ W1l, const float* __restrict__ b1l,
    const float* __restrict__ W2l, const float* __restrict__ b2l) {
    __shared__ float h1s[4][RPG][64];
    __shared__ float h2s[4][RPG][64];
    int t = threadIdx.x;
    int wave = t >> 6, lane = t & 63;
    int gw = (blockIdx.x * 256 + t) >> 6;
    int nw = (gridDim.x * 256) >> 6;
    float bsum = b1l[lane] + b2l[lane];
    const float4* __restrict__ w1r = (const float4*)(W1l + (size_t)lane * 64);
    const float4* __restrict__ w2r = (const float4*)(W2l + (size_t)lane * 64);
    for (int g = gw; g < NGROUP; g += nw) {
        int r0 = g * RPG;
        int4 rp = *(const int4*)(row_ptr + r0);     // r0 % 4 == 0 -> 16B aligned
        int rlast = row_ptr[r0 + 4];
        int eb[5] = {rp.x, rp.y, rp.z, rp.w, rlast};
        // ---- edge phase: accumulate agg for 4 rows ----
#pragma unroll
        for (int m = 0; m < RPG; ++m) {
            int r = r0 + m;
            float f = fin[((size_t)r << 6) | lane];
            float a0 = 0.f, a1 = 0.f;
            for (int j = eb[m]; j < eb[m + 1]; j += 8) {   // j always mult of 8
                int4 p0 = *(const int4*)(edges + j);
                int4 p1 = *(const int4*)(edges + j + 2);
                int4 p2 = *(const int4*)(edges + j + 4);
                int4 p3 = *(const int4*)(edges + j + 6);
                float g0 = fin[((size_t)p0.x << 6) | lane];
                float g1 = fin[((size_t)p0.z << 6) | lane];
                float g2 = fin[((size_t)p1.x << 6) | lane];
                float g3 = fin[((size_t)p1.z << 6) | lane];
                float g4 = fin[((size_t)p2.x << 6) | lane];
                float g5 = fin[((size_t)p2.z << 6) | lane];
                float g6 = fin[((size_t)p3.x << 6) | lane];
                float g7 = fin[((size_t)p3.z << 6) | lane];
                a0 += __int_as_float(p0.y) * g0;
                a1 += __int_as_float(p0.w) * g1;
                a0 += __int_as_float(p1.y) * g2;
                a1 += __int_as_float(p1.w) * g3;
                a0 += __int_as_float(p2.y) * g4;
                a1 += __int_as_float(p2.w) * g5;
                a0 += __int_as_float(p3.y) * g6;
                a1 += __int_as_float(p3.w) * g7;
            }
            float acc = a0 + a1;
            h1s[wave][m][lane] = acc + f;
            h2s[wave][m][lane] = acc * f;
        }
        // ---- dense phase (wave-local LDS RAW: compiler inserts lgkmcnt) ----
        float o0[RPG], o1[RPG];
#pragma unroll
        for (int m = 0; m < RPG; ++m) { o0[m] = bsum; o1[m] = 0.f; }
        const float4* h1r = (const float4*)&h1s[wave][0][0];
        const float4* h2r = (const float4*)&h2s[wave][0][0];
#pragma unroll 4
        for (int kk = 0; kk < 16; ++kk) {
            float4 w1v = w1r[kk];
            float4 w2v = w2r[kk];
#pragma unroll
            for (int m = 0; m < RPG; ++m) {
                float4 p = h1r[m * 16 + kk];   // same addr all lanes: broadcast
                float4 q = h2r[m * 16 + kk];
                o0[m] += w1v.x * p.x; o1[m] += w1v.y * p.y;
                o0[m] += w1v.z * p.z; o1[m] += w1v.w * p.w;
                o0[m] += w2v.x * q.x; o1[m] += w2v.y * q.y;
                o0[m] += w2v.z * q.z; o1[m] += w2v.w * q.w;
            }
        }
#pragma unroll
        for (int m = 0; m < RPG; ++m) {
            float o = o0[m] + o1[m];
            o = (o > 0.f) ? o : NEG_SLOPE * o;
            fout[((size_t)(r0 + m) << 6) | lane] = o;
        }
    }
}

// gather the 8192 selected rows (4096 users, 4096 items) of this layer's output
__global__ void gather_kernel(float* __restrict__ dst, const float* __restrict__ src,
                              const int* __restrict__ users, const int* __restrict__ items) {
    int t = threadIdx.x;
    int p = blockIdx.x * 4 + (t >> 6);
    int lane = t & 63;
    if (p < 2 * BPAIR) {
        int node = (p < BPAIR) ? users[p] : (N_USER + items[p - BPAIR]);
        dst[((size_t)p << 6) | lane] = src[((size_t)node << 6) | lane];
    }
}

// one wave per pair: lane d computes user_emb[d], item_emb[d] with float4
// reads of lane's own Wt row (64 KB matrix, L1/L2-hot); 64-lane reduce.
__global__ __launch_bounds__(256) void score_kernel(
    const float* __restrict__ features, const float* __restrict__ sel,
    const int* __restrict__ users, const int* __restrict__ items,
    const float* __restrict__ Wt, const float* __restrict__ bt,
    float* __restrict__ out) {
    __shared__ float hu[4][256];
    __shared__ float hv[4][256];
    int t = threadIdx.x;
    int wave = t >> 6, lane = t & 63;
    int gwave = (blockIdx.x * 256 + t) >> 6;
    int nwave = (gridDim.x * 256) >> 6;
    float btv = bt[lane];
    const float4* wrow = (const float4*)(Wt + (size_t)lane * 256);
    for (int p = gwave; p < BPAIR; p += nwave) {
        int u = users[p];
        int v = N_USER + items[p];
        hu[wave][lane] = features[((size_t)u << 6) | lane];
        hv[wave][lane] = features[((size_t)v << 6) | lane];
#pragma unroll
        for (int l = 0; l < 3; ++l) {
            hu[wave][64 + l * 64 + lane] = sel[(((size_t)l * 2 * BPAIR + p) << 6) | lane];
            hv[wave][64 + l * 64 + lane] = sel[(((size_t)l * 2 * BPAIR + BPAIR + p) << 6) | lane];
        }
        // wave-local LDS RAW: compiler inserts lgkmcnt wait; no barrier needed
        const float4* hu4 = (const float4*)&hu[wave][0];
        const float4* hv4 = (const float4*)&hv[wave][0];
        float pu0 = btv, pu1 = 0.f, pv0 = btv, pv1 = 0.f;
#pragma unroll 8
        for (int kk = 0; kk < 64; ++kk) {
            float4 w = wrow[kk];
            float4 a = hu4[kk];
            float4 b = hv4[kk];
            pu0 += w.x * a.x + w.z * a.z;
            pu1 += w.y * a.y + w.w * a.w;
            pv0 += w.x * b.x + w.z * b.z;
            pv1 += w.y * b.y + w.w * b.w;
        }
        float s = (pu0 + pu1) * (pv0 + pv1);
        for (int m = 32; m >= 1; m >>= 1) s += __shfl_xor(s, m, 64);
        if (lane == 0) out[p] = s;
    }
}

extern "C" void kernel_launch(void* const* d_in, const int* in_sizes, int n_in,
                              void* d_out, int out_size, void* d_ws, size_t ws_size,
                              hipStream_t stream) {
    const float* features = (const float*)d_in[0];
    const int*   rows     = (const int*)d_in[1];
    const int*   cols     = (const int*)d_in[2];
    const float* vals     = (const float*)d_in[3];
    const int*   users    = (const int*)d_in[4];
    const int*   items    = (const int*)d_in[5];
    const float* W1       = (const float*)d_in[6];
    const float* b1       = (const float*)d_in[7];
    const float* W2       = (const float*)d_in[8];
    const float* b2       = (const float*)d_in[9];
    const float* Wt       = (const float*)d_in[10];
    const float* bt       = (const float*)d_in[11];
    float* out = (float*)d_out;

    char* ws = (char*)d_ws;
    size_t off = 0;
    auto alloc = [&](size_t bytes) -> void* {
        void* p = ws + off;
        off += (bytes + 255) & ~(size_t)255;
        return p;
    };
    int*   row_ptr = (int*)alloc((N_NODE + 8) * sizeof(int));
    int*   cnt     = (int*)alloc(N_NODE * sizeof(int));
    int*   rank    = (int*)alloc((size_t)N_EDGE * sizeof(int));
    int*   bsums   = (int*)alloc(4096);
    int2*  edges   = (int2*)alloc((size_t)EPAD_CAP * sizeof(int2));
    float* f0      = (float*)alloc((size_t)N_NODE * DIM * sizeof(float));
    float* f1      = (float*)alloc((size_t)N_NODE * DIM * sizeof(float));
    float* sel     = (float*)alloc((size_t)3 * 2 * BPAIR * DIM * sizeof(float));

    hipMemsetAsync(cnt, 0, (size_t)N_NODE * sizeof(int), stream);
    hipMemsetAsync(edges, 0, (size_t)EPAD_CAP * sizeof(int2), stream);

    int eblocks = (N_EDGE + 255) / 256;
    int nblk = (N_NODE + 255) / 256;  // 586 <= 1024
    count_rank_kernel<<<eblocks, 256, 0, stream>>>(rows, cnt, rank);
    scan1_kernel<<<nblk, 256, 0, stream>>>(cnt, row_ptr + 1, bsums);
    scan2_kernel<<<1, 1024, 0, stream>>>(bsums, nblk);
    scan3_kernel<<<nblk, 256, 0, stream>>>(row_ptr, bsums);
    scatter_kernel<<<eblocks, 256, 0, stream>>>(rows, cols, vals, rank, row_ptr, edges);

    const float* fin = features;
    float* fbuf[2] = {f0, f1};
    for (int l = 0; l < 3; ++l) {
        float* fout = fbuf[l & 1];
        layer_kernel<<<2048, 256, 0, stream>>>(row_ptr, edges, fin, fout,
                                               W1 + (size_t)l * DIM * DIM, b1 + (size_t)l * DIM,
                                               W2 + (size_t)l * DIM * DIM, b2 + (size_t)l * DIM);
        gather_kernel<<<(2 * BPAIR) / 4, 256, 0, stream>>>(sel + (size_t)l * 2 * BPAIR * DIM,
                                                           fout, users, items);
        fin = fout;
    }
    score_kernel<<<256, 256, 0, stream>>>(features, sel, users, items, Wt, bt, out);
}

// Round 7
// 955.906 us; speedup vs baseline: 3.3214x; 1.0776x over previous
//
#include <hip/hip_runtime.h>

#define N_USER 100000
#define N_NODE 150000
#define N_EDGE 2400000
#define DIM 64
#define BPAIR 4096
#define NEG_SLOPE 0.01f
#define RPG 4                              // rows per wave-group (150000 % 4 == 0)
#define NGROUP (N_NODE / RPG)              // 37500
#define EPAD_CAP (N_EDGE + 8 * N_NODE)     // padded CSR capacity

// ---------------- CSR build (padded to 8-edge multiples per row) ----------------
// rank[i] = arrival order within row (from count pass) -> scatter needs no atomics.

__global__ void count_rank_kernel(const int* __restrict__ rows, int* __restrict__ cnt,
                                  int* __restrict__ rank) {
    int i = blockIdx.x * blockDim.x + threadIdx.x;
    if (i < N_EDGE) rank[i] = atomicAdd(&cnt[rows[i]], 1);
}

// scan of PADDED counts ((cnt+7)&~7); incl = row_ptr + 1
__global__ void scan1_kernel(const int* __restrict__ cnt, int* __restrict__ incl,
                             int* __restrict__ bsums) {
    __shared__ int s[256];
    int t = threadIdx.x;
    int i = blockIdx.x * 256 + t;
    s[t] = (i < N_NODE) ? ((cnt[i] + 7) & ~7) : 0;
    __syncthreads();
    for (int off = 1; off < 256; off <<= 1) {
        int add = (t >= off) ? s[t - off] : 0;
        __syncthreads();
        s[t] += add;
        __syncthreads();
    }
    if (i < N_NODE) incl[i] = s[t];
    if (t == 255) bsums[blockIdx.x] = s[255];
}

__global__ void scan2_kernel(int* __restrict__ bsums, int nblk) {
    __shared__ int s[1024];
    int t = threadIdx.x;
    s[t] = (t < nblk) ? bsums[t] : 0;
    __syncthreads();
    for (int off = 1; off < 1024; off <<= 1) {
        int add = (t >= off) ? s[t - off] : 0;
        __syncthreads();
        s[t] += add;
        __syncthreads();
    }
    if (t < nblk) bsums[t] = s[t];
}

__global__ void scan3_kernel(int* __restrict__ row_ptr, const int* __restrict__ bsums) {
    int i = blockIdx.x * 256 + threadIdx.x;
    if (i == 0) row_ptr[0] = 0;
    if (i < N_NODE && blockIdx.x > 0) row_ptr[1 + i] += bsums[blockIdx.x - 1];
}

// edges buffer pre-zeroed -> pad slots are (col=0, val=0), harmless in SpMM
__global__ void scatter_kernel(const int* __restrict__ rows, const int* __restrict__ cols,
                               const float* __restrict__ vals, const int* __restrict__ rank,
                               const int* __restrict__ row_ptr, int2* __restrict__ edges) {
    int i = blockIdx.x * blockDim.x + threadIdx.x;
    if (i < N_EDGE) {
        int p = row_ptr[rows[i]] + rank[i];
        edges[p] = make_int2(cols[i], __float_as_int(vals[i]));
    }
}

// ---------------- fused SpMM + dense layer ----------------
// One wave per 4-row group, lane d owns feature dim d.
// Edge phase: TWO rows interleaved -> two independent dep chains
//   (8 int4 edge-loads + 16 gathers outstanding); one row's ~500cy L3
//   gather latency hides under the other's addr calc + FMAs. Rows padded
//   to 8-edge multiples -> no predication inside chunks; uniform branches.
// Dense phase: W1/W2 read from GLOBAL as float4 (row-major [d][k] is the
//   per-lane layout; 32KB, L1/L2-hot) -> no LDS staging, no barrier.
//   h broadcast via same-address float4 LDS reads, amortized over 4 rows.
// NOTE: plain __launch_bounds__(256). A min-waves 2nd arg makes this
// toolchain cap VGPR at 256/arg2 (rounds 2 & 5: 8->32, 4->64) and spill.
// Occupancy measured ~42% for VGPR 52..64 -> growing to ~90 live is free.
__global__ __launch_bounds__(256) void layer_kernel(
    const int* __restrict__ row_ptr, const int2* __restrict__ edges,
    const float* __restrict__ fin, float* __restrict__ fout,
    const float* __restrict__ W1l, const float* __restrict__ b1l,
    const float* __restrict__ W2l, const float* __restrict__ b2l) {
    __shared__ float h1s[4][RPG][64];
    __shared__ float h2s[4][RPG][64];
    int t = threadIdx.x;
    int wave = t >> 6, lane = t & 63;
    int gw = (blockIdx.x * 256 + t) >> 6;
    int nw = (gridDim.x * 256) >> 6;
    float bsum = b1l[lane] + b2l[lane];
    const float4* __restrict__ w1r = (const float4*)(W1l + (size_t)lane * 64);
    const float4* __restrict__ w2r = (const float4*)(W2l + (size_t)lane * 64);
    for (int g = gw; g < NGROUP; g += nw) {
        int r0 = g * RPG;
        int4 rp = *(const int4*)(row_ptr + r0);     // r0 % 4 == 0 -> 16B aligned
        int rlast = row_ptr[r0 + 4];
        int eb[5] = {rp.x, rp.y, rp.z, rp.w, rlast};
        // ---- edge phase: 2 rows in flight ----
#pragma unroll
        for (int mp = 0; mp < RPG; mp += 2) {
            float fA = fin[((size_t)(r0 + mp) << 6) | lane];
            float fB = fin[((size_t)(r0 + mp + 1) << 6) | lane];
            float aA0 = 0.f, aA1 = 0.f, aB0 = 0.f, aB1 = 0.f;
            int jA = eb[mp],     eA = eb[mp + 1];
            int jB = eb[mp + 1], eB = eb[mp + 2];
            while (jA < eA && jB < eB) {          // wave-uniform
                int4 pa0 = *(const int4*)(edges + jA);
                int4 pa1 = *(const int4*)(edges + jA + 2);
                int4 pa2 = *(const int4*)(edges + jA + 4);
                int4 pa3 = *(const int4*)(edges + jA + 6);
                int4 pb0 = *(const int4*)(edges + jB);
                int4 pb1 = *(const int4*)(edges + jB + 2);
                int4 pb2 = *(const int4*)(edges + jB + 4);
                int4 pb3 = *(const int4*)(edges + jB + 6);
                float gA0 = fin[((size_t)pa0.x << 6) | lane];
                float gA1 = fin[((size_t)pa0.z << 6) | lane];
                float gA2 = fin[((size_t)pa1.x << 6) | lane];
                float gA3 = fin[((size_t)pa1.z << 6) | lane];
                float gA4 = fin[((size_t)pa2.x << 6) | lane];
                float gA5 = fin[((size_t)pa2.z << 6) | lane];
                float gA6 = fin[((size_t)pa3.x << 6) | lane];
                float gA7 = fin[((size_t)pa3.z << 6) | lane];
                float gB0 = fin[((size_t)pb0.x << 6) | lane];
                float gB1 = fin[((size_t)pb0.z << 6) | lane];
                float gB2 = fin[((size_t)pb1.x << 6) | lane];
                float gB3 = fin[((size_t)pb1.z << 6) | lane];
                float gB4 = fin[((size_t)pb2.x << 6) | lane];
                float gB5 = fin[((size_t)pb2.z << 6) | lane];
                float gB6 = fin[((size_t)pb3.x << 6) | lane];
                float gB7 = fin[((size_t)pb3.z << 6) | lane];
                aA0 += __int_as_float(pa0.y) * gA0;
                aA1 += __int_as_float(pa0.w) * gA1;
                aA0 += __int_as_float(pa1.y) * gA2;
                aA1 += __int_as_float(pa1.w) * gA3;
                aA0 += __int_as_float(pa2.y) * gA4;
                aA1 += __int_as_float(pa2.w) * gA5;
                aA0 += __int_as_float(pa3.y) * gA6;
                aA1 += __int_as_float(pa3.w) * gA7;
                aB0 += __int_as_float(pb0.y) * gB0;
                aB1 += __int_as_float(pb0.w) * gB1;
                aB0 += __int_as_float(pb1.y) * gB2;
                aB1 += __int_as_float(pb1.w) * gB3;
                aB0 += __int_as_float(pb2.y) * gB4;
                aB1 += __int_as_float(pb2.w) * gB5;
                aB0 += __int_as_float(pb3.y) * gB6;
                aB1 += __int_as_float(pb3.w) * gB7;
                jA += 8; jB += 8;
            }
            for (; jA < eA; jA += 8) {            // tail: row A alone
                int4 p0 = *(const int4*)(edges + jA);
                int4 p1 = *(const int4*)(edges + jA + 2);
                int4 p2 = *(const int4*)(edges + jA + 4);
                int4 p3 = *(const int4*)(edges + jA + 6);
                float g0 = fin[((size_t)p0.x << 6) | lane];
                float g1 = fin[((size_t)p0.z << 6) | lane];
                float g2 = fin[((size_t)p1.x << 6) | lane];
                float g3 = fin[((size_t)p1.z << 6) | lane];
                float g4 = fin[((size_t)p2.x << 6) | lane];
                float g5 = fin[((size_t)p2.z << 6) | lane];
                float g6 = fin[((size_t)p3.x << 6) | lane];
                float g7 = fin[((size_t)p3.z << 6) | lane];
                aA0 += __int_as_float(p0.y) * g0;
                aA1 += __int_as_float(p0.w) * g1;
                aA0 += __int_as_float(p1.y) * g2;
                aA1 += __int_as_float(p1.w) * g3;
                aA0 += __int_as_float(p2.y) * g4;
                aA1 += __int_as_float(p2.w) * g5;
                aA0 += __int_as_float(p3.y) * g6;
                aA1 += __int_as_float(p3.w) * g7;
            }
            for (; jB < eB; jB += 8) {            // tail: row B alone
                int4 p0 = *(const int4*)(edges + jB);
                int4 p1 = *(const int4*)(edges + jB + 2);
                int4 p2 = *(const int4*)(edges + jB + 4);
                int4 p3 = *(const int4*)(edges + jB + 6);
                float g0 = fin[((size_t)p0.x << 6) | lane];
                float g1 = fin[((size_t)p0.z << 6) | lane];
                float g2 = fin[((size_t)p1.x << 6) | lane];
                float g3 = fin[((size_t)p1.z << 6) | lane];
                float g4 = fin[((size_t)p2.x << 6) | lane];
                float g5 = fin[((size_t)p2.z << 6) | lane];
                float g6 = fin[((size_t)p3.x << 6) | lane];
                float g7 = fin[((size_t)p3.z << 6) | lane];
                aB0 += __int_as_float(p0.y) * g0;
                aB1 += __int_as_float(p0.w) * g1;
                aB0 += __int_as_float(p1.y) * g2;
                aB1 += __int_as_float(p1.w) * g3;
                aB0 += __int_as_float(p2.y) * g4;
                aB1 += __int_as_float(p2.w) * g5;
                aB0 += __int_as_float(p3.y) * g6;
                aB1 += __int_as_float(p3.w) * g7;
            }
            float accA = aA0 + aA1;
            float accB = aB0 + aB1;
            h1s[wave][mp][lane]     = accA + fA;
            h2s[wave][mp][lane]     = accA * fA;
            h1s[wave][mp + 1][lane] = accB + fB;
            h2s[wave][mp + 1][lane] = accB * fB;
        }
        // ---- dense phase (wave-local LDS RAW: compiler inserts lgkmcnt) ----
        float o0[RPG], o1[RPG];
#pragma unroll
        for (int m = 0; m < RPG; ++m) { o0[m] = bsum; o1[m] = 0.f; }
        const float4* h1r = (const float4*)&h1s[wave][0][0];
        const float4* h2r = (const float4*)&h2s[wave][0][0];
#pragma unroll 4
        for (int kk = 0; kk < 16; ++kk) {
            float4 w1v = w1r[kk];
            float4 w2v = w2r[kk];
#pragma unroll
            for (int m = 0; m < RPG; ++m) {
                float4 p = h1r[m * 16 + kk];   // same addr all lanes: broadcast
                float4 q = h2r[m * 16 + kk];
                o0[m] += w1v.x * p.x; o1[m] += w1v.y * p.y;
                o0[m] += w1v.z * p.z; o1[m] += w1v.w * p.w;
                o0[m] += w2v.x * q.x; o1[m] += w2v.y * q.y;
                o0[m] += w2v.z * q.z; o1[m] += w2v.w * q.w;
            }
        }
#pragma unroll
        for (int m = 0; m < RPG; ++m) {
            float o = o0[m] + o1[m];
            o = (o > 0.f) ? o : NEG_SLOPE * o;
            fout[((size_t)(r0 + m) << 6) | lane] = o;
        }
    }
}

// gather the 8192 selected rows (4096 users, 4096 items) of this layer's output
__global__ void gather_kernel(float* __restrict__ dst, const float* __restrict__ src,
                              const int* __restrict__ users, const int* __restrict__ items) {
    int t = threadIdx.x;
    int p = blockIdx.x * 4 + (t >> 6);
    int lane = t & 63;
    if (p < 2 * BPAIR) {
        int node = (p < BPAIR) ? users[p] : (N_USER + items[p - BPAIR]);
        dst[((size_t)p << 6) | lane] = src[((size_t)node << 6) | lane];
    }
}

// one wave per pair: lane d computes user_emb[d], item_emb[d] with float4
// reads of lane's own Wt row (64 KB matrix, L1/L2-hot); 64-lane reduce.
__global__ __launch_bounds__(256) void score_kernel(
    const float* __restrict__ features, const float* __restrict__ sel,
    const int* __restrict__ users, const int* __restrict__ items,
    const float* __restrict__ Wt, const float* __restrict__ bt,
    float* __restrict__ out) {
    __shared__ float hu[4][256];
    __shared__ float hv[4][256];
    int t = threadIdx.x;
    int wave = t >> 6, lane = t & 63;
    int gwave = (blockIdx.x * 256 + t) >> 6;
    int nwave = (gridDim.x * 256) >> 6;
    float btv = bt[lane];
    const float4* wrow = (const float4*)(Wt + (size_t)lane * 256);
    for (int p = gwave; p < BPAIR; p += nwave) {
        int u = users[p];
        int v = N_USER + items[p];
        hu[wave][lane] = features[((size_t)u << 6) | lane];
        hv[wave][lane] = features[((size_t)v << 6) | lane];
#pragma unroll
        for (int l = 0; l < 3; ++l) {
            hu[wave][64 + l * 64 + lane] = sel[(((size_t)l * 2 * BPAIR + p) << 6) | lane];
            hv[wave][64 + l * 64 + lane] = sel[(((size_t)l * 2 * BPAIR + BPAIR + p) << 6) | lane];
        }
        // wave-local LDS RAW: compiler inserts lgkmcnt wait; no barrier needed
        const float4* hu4 = (const float4*)&hu[wave][0];
        const float4* hv4 = (const float4*)&hv[wave][0];
        float pu0 = btv, pu1 = 0.f, pv0 = btv, pv1 = 0.f;
#pragma unroll 8
        for (int kk = 0; kk < 64; ++kk) {
            float4 w = wrow[kk];
            float4 a = hu4[kk];
            float4 b = hv4[kk];
            pu0 += w.x * a.x + w.z * a.z;
            pu1 += w.y * a.y + w.w * a.w;
            pv0 += w.x * b.x + w.z * b.z;
            pv1 += w.y * b.y + w.w * b.w;
        }
        float s = (pu0 + pu1) * (pv0 + pv1);
        for (int m = 32; m >= 1; m >>= 1) s += __shfl_xor(s, m, 64);
        if (lane == 0) out[p] = s;
    }
}

extern "C" void kernel_launch(void* const* d_in, const int* in_sizes, int n_in,
                              void* d_out, int out_size, void* d_ws, size_t ws_size,
                              hipStream_t stream) {
    const float* features = (const float*)d_in[0];
    const int*   rows     = (const int*)d_in[1];
    const int*   cols     = (const int*)d_in[2];
    const float* vals     = (const float*)d_in[3];
    const int*   users    = (const int*)d_in[4];
    const int*   items    = (const int*)d_in[5];
    const float* W1       = (const float*)d_in[6];
    const float* b1       = (const float*)d_in[7];
    const float* W2       = (const float*)d_in[8];
    const float* b2       = (const float*)d_in[9];
    const float* Wt       = (const float*)d_in[10];
    const float* bt       = (const float*)d_in[11];
    float* out = (float*)d_out;

    char* ws = (char*)d_ws;
    size_t off = 0;
    auto alloc = [&](size_t bytes) -> void* {
        void* p = ws + off;
        off += (bytes + 255) & ~(size_t)255;
        return p;
    };
    int*   row_ptr = (int*)alloc((N_NODE + 8) * sizeof(int));
    int*   cnt     = (int*)alloc(N_NODE * sizeof(int));
    int*   rank    = (int*)alloc((size_t)N_EDGE * sizeof(int));
    int*   bsums   = (int*)alloc(4096);
    int2*  edges   = (int2*)alloc((size_t)EPAD_CAP * sizeof(int2));
    float* f0      = (float*)alloc((size_t)N_NODE * DIM * sizeof(float));
    float* f1      = (float*)alloc((size_t)N_NODE * DIM * sizeof(float));
    float* sel     = (float*)alloc((size_t)3 * 2 * BPAIR * DIM * sizeof(float));

    hipMemsetAsync(cnt, 0, (size_t)N_NODE * sizeof(int), stream);
    hipMemsetAsync(edges, 0, (size_t)EPAD_CAP * sizeof(int2), stream);

    int eblocks = (N_EDGE + 255) / 256;
    int nblk = (N_NODE + 255) / 256;  // 586 <= 1024
    count_rank_kernel<<<eblocks, 256, 0, stream>>>(rows, cnt, rank);
    scan1_kernel<<<nblk, 256, 0, stream>>>(cnt, row_ptr + 1, bsums);
    scan2_kernel<<<1, 1024, 0, stream>>>(bsums, nblk);
    scan3_kernel<<<nblk, 256, 0, stream>>>(row_ptr, bsums);
    scatter_kernel<<<eblocks, 256, 0, stream>>>(rows, cols, vals, rank, row_ptr, edges);

    const float* fin = features;
    float* fbuf[2] = {f0, f1};
    for (int l = 0; l < 3; ++l) {
        float* fout = fbuf[l & 1];
        layer_kernel<<<2048, 256, 0, stream>>>(row_ptr, edges, fin, fout,
                                               W1 + (size_t)l * DIM * DIM, b1 + (size_t)l * DIM,
                                               W2 + (size_t)l * DIM * DIM, b2 + (size_t)l * DIM);
        gather_kernel<<<(2 * BPAIR) / 4, 256, 0, stream>>>(sel + (size_t)l * 2 * BPAIR * DIM,
                                                           fout, users, items);
        fin = fout;
    }
    score_kernel<<<256, 256, 0, stream>>>(features, sel, users, items, Wt, bt, out);
}

// Round 10
// 908.215 us; speedup vs baseline: 3.4958x; 1.0525x over previous
//
#include <hip/hip_runtime.h>

#define N_USER 100000
#define N_NODE 150000
#define N_EDGE 2400000
#define DIM 64
#define BPAIR 4096
#define NEG_SLOPE 0.01f
#define RPW 16                             // rows per wave (150000 % 16 == 0)
#define NG16 (N_NODE / RPW)                // 9375 groups
#define CHUNK 256                          // edges staged per LDS chunk
#define EPAD_CAP (N_EDGE + 8 * N_NODE + 2 * CHUNK)  // padded CSR + staging overrun pad

// ---------------- CSR build (padded to 8-edge multiples per row) ----------------
// rank[i] = arrival order within row (from count pass) -> scatter needs no atomics.

__global__ void count_rank_kernel(const int* __restrict__ rows, int* __restrict__ cnt,
                                  int* __restrict__ rank) {
    int i = blockIdx.x * blockDim.x + threadIdx.x;
    if (i < N_EDGE) rank[i] = atomicAdd(&cnt[rows[i]], 1);
}

// scan of PADDED counts ((cnt+7)&~7); incl = row_ptr + 1
__global__ void scan1_kernel(const int* __restrict__ cnt, int* __restrict__ incl,
                             int* __restrict__ bsums) {
    __shared__ int s[256];
    int t = threadIdx.x;
    int i = blockIdx.x * 256 + t;
    s[t] = (i < N_NODE) ? ((cnt[i] + 7) & ~7) : 0;
    __syncthreads();
    for (int off = 1; off < 256; off <<= 1) {
        int add = (t >= off) ? s[t - off] : 0;
        __syncthreads();
        s[t] += add;
        __syncthreads();
    }
    if (i < N_NODE) incl[i] = s[t];
    if (t == 255) bsums[blockIdx.x] = s[255];
}

__global__ void scan2_kernel(int* __restrict__ bsums, int nblk) {
    __shared__ int s[1024];
    int t = threadIdx.x;
    s[t] = (t < nblk) ? bsums[t] : 0;
    __syncthreads();
    for (int off = 1; off < 1024; off <<= 1) {
        int add = (t >= off) ? s[t - off] : 0;
        __syncthreads();
        s[t] += add;
        __syncthreads();
    }
    if (t < nblk) bsums[t] = s[t];
}

__global__ void scan3_kernel(int* __restrict__ row_ptr, const int* __restrict__ bsums) {
    int i = blockIdx.x * 256 + threadIdx.x;
    if (i == 0) row_ptr[0] = 0;
    if (i < N_NODE && blockIdx.x > 0) row_ptr[1 + i] += bsums[blockIdx.x - 1];
}

// edges buffer pre-zeroed -> pad slots are (col=0, val=0), harmless in SpMM
__global__ void scatter_kernel(const int* __restrict__ rows, const int* __restrict__ cols,
                               const float* __restrict__ vals, const int* __restrict__ rank,
                               const int* __restrict__ row_ptr, int2* __restrict__ edges) {
    int i = blockIdx.x * blockDim.x + threadIdx.x;
    if (i < N_EDGE) {
        int p = row_ptr[rows[i]] + rank[i];
        edges[p] = make_int2(cols[i], __float_as_int(vals[i]));
    }
}

// ---------------- fused SpMM + dense layer ----------------
// One wave per 16 consecutive rows (contiguous CSR edge range).
// Edge phase: 256-edge chunks reg-staged into LDS one chunk AHEAD
//   (4 coalesced int2 loads/lane; ~3000cy of compute hides HBM latency),
//   consumed via broadcast ds_read_b128 (uniform addr, conflict-free,
//   ~120cy on the chain instead of ~600cy VMEM). Per 8-edge sub-chunk:
//   4 ds_read_b128 + 8 independent gathers + 8 FMAs.
// Row boundaries: padded CSR -> all bounds multiples of 8; wave-uniform
//   bnd from LDS-cached row_ptr[r0..r0+16]. Every 4 rows -> dense phase.
// Dense phase: W1/W2 from GLOBAL as float4 (row-major [d][k] = per-lane
//   layout, 32KB L1-hot); h broadcast via same-addr LDS reads; no barrier
//   anywhere (all LDS traffic is wave-local; compiler inserts lgkmcnt).
// NOTE: plain __launch_bounds__(256). A min-waves 2nd arg makes this
// toolchain cap VGPR at 256/arg2 (rounds 2 & 5: 8->32, 4->64) and spill.
__global__ __launch_bounds__(256) void layer_kernel(
    const int* __restrict__ row_ptr, const int2* __restrict__ edges,
    const float* __restrict__ fin, float* __restrict__ fout,
    const float* __restrict__ W1l, const float* __restrict__ b1l,
    const float* __restrict__ W2l, const float* __restrict__ b2l) {
    __shared__ int2  ebuf[4][CHUNK];      // 8 KB: per-wave edge chunk
    __shared__ float h1s[4][4][64];       // 4 KB
    __shared__ float h2s[4][4][64];       // 4 KB
    __shared__ int   rbnd[4][20];         // row bounds cache
    int t = threadIdx.x, wave = t >> 6, lane = t & 63;
    int g = blockIdx.x * 4 + wave;
    if (g >= NG16) return;
    int r0 = g * RPW;
    float bsum = b1l[lane] + b2l[lane];
    const float4* __restrict__ w1r = (const float4*)(W1l + (size_t)lane * 64);
    const float4* __restrict__ w2r = (const float4*)(W2l + (size_t)lane * 64);

    if (lane < 17) rbnd[wave][lane] = row_ptr[r0 + lane];
    // wave-local LDS RAW below: compiler inserts lgkmcnt waits; no barrier.
    int estart = rbnd[wave][0];
    int eend   = rbnd[wave][16];
    int nch = (eend - estart + CHUNK - 1) / CHUNK;

    int m = 0;                      // current row within group (uniform)
    int bnd = rbnd[wave][1];        // end (exclusive) of current row's edges
    float acc0 = 0.f, acc1 = 0.f;
    float fcur = fin[((size_t)r0 << 6) | lane];

    auto dense_batch = [&]() {      // rows r0+m-4 .. r0+m-1 (h slots 0..3)
        float o0[4], o1[4];
#pragma unroll
        for (int mm = 0; mm < 4; ++mm) { o0[mm] = bsum; o1[mm] = 0.f; }
        const float4* h1r = (const float4*)&h1s[wave][0][0];
        const float4* h2r = (const float4*)&h2s[wave][0][0];
#pragma unroll 4
        for (int kk = 0; kk < 16; ++kk) {
            float4 w1v = w1r[kk];
            float4 w2v = w2r[kk];
#pragma unroll
            for (int mm = 0; mm < 4; ++mm) {
                float4 p = h1r[mm * 16 + kk];   // same addr all lanes: broadcast
                float4 q = h2r[mm * 16 + kk];
                o0[mm] += w1v.x * p.x; o1[mm] += w1v.y * p.y;
                o0[mm] += w1v.z * p.z; o1[mm] += w1v.w * p.w;
                o0[mm] += w2v.x * q.x; o1[mm] += w2v.y * q.y;
                o0[mm] += w2v.z * q.z; o1[mm] += w2v.w * q.w;
            }
        }
        int rb = r0 + m - 4;
#pragma unroll
        for (int mm = 0; mm < 4; ++mm) {
            float o = o0[mm] + o1[mm];
            o = (o > 0.f) ? o : NEG_SLOPE * o;
            fout[((size_t)(rb + mm) << 6) | lane] = o;
        }
    };

    // prologue: stage chunk 0 into regs (may over-read; edges has +2*CHUNK pad)
    const int2* ep = edges + estart;
    int2 s0 = ep[lane], s1 = ep[lane + 64], s2 = ep[lane + 128], s3 = ep[lane + 192];

    for (int c = 0; c < nch; ++c) {
        int2* eb = &ebuf[wave][0];
        eb[lane] = s0; eb[lane + 64] = s1; eb[lane + 128] = s2; eb[lane + 192] = s3;
        if (c + 1 < nch) {          // issue next chunk's loads NOW; hidden by
            const int2* ep2 = edges + estart + (c + 1) * CHUNK;   // this chunk's work
            s0 = ep2[lane]; s1 = ep2[lane + 64]; s2 = ep2[lane + 128]; s3 = ep2[lane + 192];
        }
        int cbase = estart + c * CHUNK;
        int rem = eend - cbase;
        int cnt = rem < CHUNK ? rem : CHUNK;    // multiple of 8
        for (int k = 0; k < cnt; k += 8) {
            while (cbase + k == bnd) {          // row finished (uniform; m stays <16 here)
                float a = acc0 + acc1;
                h1s[wave][m & 3][lane] = a + fcur;
                h2s[wave][m & 3][lane] = a * fcur;
                acc0 = 0.f; acc1 = 0.f;
                ++m;
                if ((m & 3) == 0) dense_batch();
                fcur = fin[((size_t)(r0 + m) << 6) | lane];
                bnd = rbnd[wave][m + 1];
            }
            int4 e01 = *(const int4*)(eb + k);      // broadcast ds_read_b128
            int4 e23 = *(const int4*)(eb + k + 2);
            int4 e45 = *(const int4*)(eb + k + 4);
            int4 e67 = *(const int4*)(eb + k + 6);
            float g0 = fin[((size_t)e01.x << 6) | lane];
            float g1 = fin[((size_t)e01.z << 6) | lane];
            float g2 = fin[((size_t)e23.x << 6) | lane];
            float g3 = fin[((size_t)e23.z << 6) | lane];
            float g4 = fin[((size_t)e45.x << 6) | lane];
            float g5 = fin[((size_t)e45.z << 6) | lane];
            float g6 = fin[((size_t)e67.x << 6) | lane];
            float g7 = fin[((size_t)e67.z << 6) | lane];
            acc0 += __int_as_float(e01.y) * g0;
            acc1 += __int_as_float(e01.w) * g1;
            acc0 += __int_as_float(e23.y) * g2;
            acc1 += __int_as_float(e23.w) * g3;
            acc0 += __int_as_float(e45.y) * g4;
            acc1 += __int_as_float(e45.w) * g5;
            acc0 += __int_as_float(e67.y) * g6;
            acc1 += __int_as_float(e67.w) * g7;
        }
    }
    // finalize remaining rows (last row always lands here; also empty tail rows)
    while (m < RPW) {
        float a = acc0 + acc1;
        h1s[wave][m & 3][lane] = a + fcur;
        h2s[wave][m & 3][lane] = a * fcur;
        acc0 = 0.f; acc1 = 0.f;
        ++m;
        if ((m & 3) == 0) dense_batch();
        if (m < RPW) fcur = fin[((size_t)(r0 + m) << 6) | lane];
    }
}

// gather the 8192 selected rows (4096 users, 4096 items) of this layer's output
__global__ void gather_kernel(float* __restrict__ dst, const float* __restrict__ src,
                              const int* __restrict__ users, const int* __restrict__ items) {
    int t = threadIdx.x;
    int p = blockIdx.x * 4 + (t >> 6);
    int lane = t & 63;
    if (p < 2 * BPAIR) {
        int node = (p < BPAIR) ? users[p] : (N_USER + items[p - BPAIR]);
        dst[((size_t)p << 6) | lane] = src[((size_t)node << 6) | lane];
    }
}

// one wave per pair: lane d computes user_emb[d], item_emb[d] with float4
// reads of lane's own Wt row (64 KB matrix, L1/L2-hot); 64-lane reduce.
__global__ __launch_bounds__(256) void score_kernel(
    const float* __restrict__ features, const float* __restrict__ sel,
    const int* __restrict__ users, const int* __restrict__ items,
    const float* __restrict__ Wt, const float* __restrict__ bt,
    float* __restrict__ out) {
    __shared__ float hu[4][256];
    __shared__ float hv[4][256];
    int t = threadIdx.x;
    int wave = t >> 6, lane = t & 63;
    int gwave = (blockIdx.x * 256 + t) >> 6;
    int nwave = (gridDim.x * 256) >> 6;
    float btv = bt[lane];
    const float4* wrow = (const float4*)(Wt + (size_t)lane * 256);
    for (int p = gwave; p < BPAIR; p += nwave) {
        int u = users[p];
        int v = N_USER + items[p];
        hu[wave][lane] = features[((size_t)u << 6) | lane];
        hv[wave][lane] = features[((size_t)v << 6) | lane];
#pragma unroll
        for (int l = 0; l < 3; ++l) {
            hu[wave][64 + l * 64 + lane] = sel[(((size_t)l * 2 * BPAIR + p) << 6) | lane];
            hv[wave][64 + l * 64 + lane] = sel[(((size_t)l * 2 * BPAIR + BPAIR + p) << 6) | lane];
        }
        // wave-local LDS RAW: compiler inserts lgkmcnt wait; no barrier needed
        const float4* hu4 = (const float4*)&hu[wave][0];
        const float4* hv4 = (const float4*)&hv[wave][0];
        float pu0 = btv, pu1 = 0.f, pv0 = btv, pv1 = 0.f;
#pragma unroll 8
        for (int kk = 0; kk < 64; ++kk) {
            float4 w = wrow[kk];
            float4 a = hu4[kk];
            float4 b = hv4[kk];
            pu0 += w.x * a.x + w.z * a.z;
            pu1 += w.y * a.y + w.w * a.w;
            pv0 += w.x * b.x + w.z * b.z;
            pv1 += w.y * b.y + w.w * b.w;
        }
        float s = (pu0 + pu1) * (pv0 + pv1);
        for (int m = 32; m >= 1; m >>= 1) s += __shfl_xor(s, m, 64);
        if (lane == 0) out[p] = s;
    }
}

extern "C" void kernel_launch(void* const* d_in, const int* in_sizes, int n_in,
                              void* d_out, int out_size, void* d_ws, size_t ws_size,
                              hipStream_t stream) {
    const float* features = (const float*)d_in[0];
    const int*   rows     = (const int*)d_in[1];
    const int*   cols     = (const int*)d_in[2];
    const float* vals     = (const float*)d_in[3];
    const int*   users    = (const int*)d_in[4];
    const int*   items    = (const int*)d_in[5];
    const float* W1       = (const float*)d_in[6];
    const float* b1       = (const float*)d_in[7];
    const float* W2       = (const float*)d_in[8];
    const float* b2       = (const float*)d_in[9];
    const float* Wt       = (const float*)d_in[10];
    const float* bt       = (const float*)d_in[11];
    float* out = (float*)d_out;

    char* ws = (char*)d_ws;
    size_t off = 0;
    auto alloc = [&](size_t bytes) -> void* {
        void* p = ws + off;
        off += (bytes + 255) & ~(size_t)255;
        return p;
    };
    int*   row_ptr = (int*)alloc((N_NODE + 8) * sizeof(int));
    int*   cnt     = (int*)alloc(N_NODE * sizeof(int));
    int*   rank    = (int*)alloc((size_t)N_EDGE * sizeof(int));
    int*   bsums   = (int*)alloc(4096);
    int2*  edges   = (int2*)alloc((size_t)EPAD_CAP * sizeof(int2));
    float* f0      = (float*)alloc((size_t)N_NODE * DIM * sizeof(float));
    float* f1      = (float*)alloc((size_t)N_NODE * DIM * sizeof(float));
    float* sel     = (float*)alloc((size_t)3 * 2 * BPAIR * DIM * sizeof(float));

    hipMemsetAsync(cnt, 0, (size_t)N_NODE * sizeof(int), stream);
    hipMemsetAsync(edges, 0, (size_t)EPAD_CAP * sizeof(int2), stream);

    int eblocks = (N_EDGE + 255) / 256;
    int nblk = (N_NODE + 255) / 256;  // 586 <= 1024
    count_rank_kernel<<<eblocks, 256, 0, stream>>>(rows, cnt, rank);
    scan1_kernel<<<nblk, 256, 0, stream>>>(cnt, row_ptr + 1, bsums);
    scan2_kernel<<<1, 1024, 0, stream>>>(bsums, nblk);
    scan3_kernel<<<nblk, 256, 0, stream>>>(row_ptr, bsums);
    scatter_kernel<<<eblocks, 256, 0, stream>>>(rows, cols, vals, rank, row_ptr, edges);

    const float* fin = features;
    float* fbuf[2] = {f0, f1};
    int lblocks = (NG16 + 3) / 4;   // 2344 blocks x 4 waves, one 16-row group each
    for (int l = 0; l < 3; ++l) {
        float* fout = fbuf[l & 1];
        layer_kernel<<<lblocks, 256, 0, stream>>>(row_ptr, edges, fin, fout,
                                                  W1 + (size_t)l * DIM * DIM, b1 + (size_t)l * DIM,
                                                  W2 + (size_t)l * DIM * DIM, b2 + (size_t)l * DIM);
        gather_kernel<<<(2 * BPAIR) / 4, 256, 0, stream>>>(sel + (size_t)l * 2 * BPAIR * DIM,
                                                           fout, users, items);
        fin = fout;
    }
    score_kernel<<<256, 256, 0, stream>>>(features, sel, users, items, Wt, bt, out);
}